// Round 4
// baseline (5369.988 us; speedup 1.0000x reference)
//
#include <hip/hip_runtime.h>

// SpikeLinear: out = LIF_scan( x @ W^T + bias ) over T=8 timesteps.
//
// Numerics (DO NOT CHANGE): must reproduce numpy/OpenBLAS sgemm bit-for-bit
// because the spike threshold (memb > 1.0) is discontinuous. OpenBLAS
// accumulates each C element as a strict sequential fp32 FMA chain over
// ascending k, blocked by kc=384: per-panel register accumulation from zero,
// then C += panel (fp32 add) at k = 384, 768, ..., 3840. fp32 bias add,
// fp32 LIF scan. Verified absmax == 0.0 in round 3.
//
// Perf: 8x8 register tile (64 FMA per 4 ds_read_b128, ~91% FMA issue),
// double-buffered LDS (1 barrier per BK step), prefetch one step ahead.

constexpr int TSTEPS = 8;
constexpr int BK     = 16;
constexpr int TILE_M = 64;    // 8 batch rows * 8 timesteps
constexpr int TILE_N = 256;   // output columns per block
constexpr int KC     = 384;   // OpenBLAS SGEMM_DEFAULT_Q on x86-64

__global__ __launch_bounds__(256, 2)
void spike_linear_f32seq(const float* __restrict__ x,
                         const float* __restrict__ w,
                         const float* __restrict__ bias,
                         float* __restrict__ out,
                         int B, int IN, int OUT)
{
    // k-major LDS tiles, double-buffered. +4 pad keeps rows 16B-aligned and
    // rotates banks by 4 per k row (2-way write aliasing only = free).
    __shared__ float xs[2][BK][TILE_M + 4];
    __shared__ float ws[2][BK][TILE_N + 4];

    const int tid = threadIdx.x;
    const int tx  = tid & 31;    // column group: 8 consecutive outputs
    const int ty  = tid >> 5;    // batch row within tile (owns all 8 t)

    const int m0 = blockIdx.y * TILE_M;
    const int n0 = blockIdx.x * TILE_N;

    float acc_tot[TSTEPS][8];    // C memory value (panel sums folded in)
    float acc_blk[TSTEPS][8];    // current kc-panel register accumulator
    #pragma unroll
    for (int t = 0; t < TSTEPS; ++t)
        #pragma unroll
        for (int c = 0; c < 8; ++c) { acc_tot[t][c] = 0.f; acc_blk[t][c] = 0.f; }

    // staging: thread -> (row sr, k-offset sk); one float4 of x, four of w
    const int sr = tid >> 2;         // 0..63
    const int sk = (tid & 3) * 4;    // 0,4,8,12

    const float* xrow  = x + (size_t)(m0 + sr) * IN + sk;
    const float* wrow0 = w + (size_t)(n0 +       sr) * IN + sk;
    const float* wrow1 = w + (size_t)(n0 +  64 + sr) * IN + sk;
    const float* wrow2 = w + (size_t)(n0 + 128 + sr) * IN + sk;
    const float* wrow3 = w + (size_t)(n0 + 192 + sr) * IN + sk;

    // prologue: stage k-step 0 into buffer 0
    {
        const float4 xv  = *(const float4*)(xrow);
        const float4 wv0 = *(const float4*)(wrow0);
        const float4 wv1 = *(const float4*)(wrow1);
        const float4 wv2 = *(const float4*)(wrow2);
        const float4 wv3 = *(const float4*)(wrow3);
        xs[0][sk+0][sr] = xv.x;  xs[0][sk+1][sr] = xv.y;
        xs[0][sk+2][sr] = xv.z;  xs[0][sk+3][sr] = xv.w;
        ws[0][sk+0][sr]     = wv0.x; ws[0][sk+1][sr]     = wv0.y;
        ws[0][sk+2][sr]     = wv0.z; ws[0][sk+3][sr]     = wv0.w;
        ws[0][sk+0][sr+64]  = wv1.x; ws[0][sk+1][sr+64]  = wv1.y;
        ws[0][sk+2][sr+64]  = wv1.z; ws[0][sk+3][sr+64]  = wv1.w;
        ws[0][sk+0][sr+128] = wv2.x; ws[0][sk+1][sr+128] = wv2.y;
        ws[0][sk+2][sr+128] = wv2.z; ws[0][sk+3][sr+128] = wv2.w;
        ws[0][sk+0][sr+192] = wv3.x; ws[0][sk+1][sr+192] = wv3.y;
        ws[0][sk+2][sr+192] = wv3.z; ws[0][sk+3][sr+192] = wv3.w;
    }
    __syncthreads();

    for (int kk = 0; kk < IN; kk += BK) {
        const int buf = (kk >> 4) & 1;

        // kc-panel boundary: fold panel into C exactly like BLAS (C += panel)
        if (kk > 0 && (kk % KC) == 0) {
            #pragma unroll
            for (int t = 0; t < TSTEPS; ++t)
                #pragma unroll
                for (int c = 0; c < 8; ++c) {
                    acc_tot[t][c] += acc_blk[t][c];
                    acc_blk[t][c] = 0.f;
                }
        }

        // prefetch next k-step from global (latency hides under the FMAs)
        const bool has_next = (kk + BK) < IN;
        float4 xv, wv0, wv1, wv2, wv3;
        if (has_next) {
            xv  = *(const float4*)(xrow  + kk + BK);
            wv0 = *(const float4*)(wrow0 + kk + BK);
            wv1 = *(const float4*)(wrow1 + kk + BK);
            wv2 = *(const float4*)(wrow2 + kk + BK);
            wv3 = *(const float4*)(wrow3 + kk + BK);
        }

        #pragma unroll
        for (int k = 0; k < BK; ++k) {
            float xr[8], wr[8];
            *(float4*)&xr[0] = *(const float4*)&xs[buf][k][ty*8];
            *(float4*)&xr[4] = *(const float4*)&xs[buf][k][ty*8 + 4];
            *(float4*)&wr[0] = *(const float4*)&ws[buf][k][tx*8];
            *(float4*)&wr[4] = *(const float4*)&ws[buf][k][tx*8 + 4];
            #pragma unroll
            for (int t = 0; t < TSTEPS; ++t)
                #pragma unroll
                for (int c = 0; c < 8; ++c)
                    acc_blk[t][c] = fmaf(xr[t], wr[c], acc_blk[t][c]);
        }

        if (has_next) {
            const int nb = buf ^ 1;
            xs[nb][sk+0][sr] = xv.x;  xs[nb][sk+1][sr] = xv.y;
            xs[nb][sk+2][sr] = xv.z;  xs[nb][sk+3][sr] = xv.w;
            ws[nb][sk+0][sr]     = wv0.x; ws[nb][sk+1][sr]     = wv0.y;
            ws[nb][sk+2][sr]     = wv0.z; ws[nb][sk+3][sr]     = wv0.w;
            ws[nb][sk+0][sr+64]  = wv1.x; ws[nb][sk+1][sr+64]  = wv1.y;
            ws[nb][sk+2][sr+64]  = wv1.z; ws[nb][sk+3][sr+64]  = wv1.w;
            ws[nb][sk+0][sr+128] = wv2.x; ws[nb][sk+1][sr+128] = wv2.y;
            ws[nb][sk+2][sr+128] = wv2.z; ws[nb][sk+3][sr+128] = wv2.w;
            ws[nb][sk+0][sr+192] = wv3.x; ws[nb][sk+1][sr+192] = wv3.y;
            ws[nb][sk+2][sr+192] = wv3.z; ws[nb][sk+3][sr+192] = wv3.w;
        }
        __syncthreads();
    }

    // final panel fold (last panel is 256 wide: 4096 = 10*384 + 256)
    #pragma unroll
    for (int t = 0; t < TSTEPS; ++t)
        #pragma unroll
        for (int c = 0; c < 8; ++c)
            acc_tot[t][c] += acc_blk[t][c];

    // epilogue: fp32 bias add (numpy order), fp32 LIF scan.
    const int bg = blockIdx.y * 8 + ty;   // global batch index
    const int o0 = n0 + tx * 8;
    const float4 bvlo = *(const float4*)(bias + o0);
    const float4 bvhi = *(const float4*)(bias + o0 + 4);
    float bb[8] = {bvlo.x, bvlo.y, bvlo.z, bvlo.w,
                   bvhi.x, bvhi.y, bvhi.z, bvhi.w};
    float memb[8] = {0.f, 0.f, 0.f, 0.f, 0.f, 0.f, 0.f, 0.f};
    #pragma unroll
    for (int t = 0; t < TSTEPS; ++t) {
        float sp[8];
        #pragma unroll
        for (int c = 0; c < 8; ++c) {
            float pre = acc_tot[t][c] + bb[c];
            memb[c] += pre;                          // VTHR = 1.0 (exact)
            float s = (memb[c] > 1.0f) ? 1.0f : 0.0f;
            memb[c] *= (1.0f - s);                   // reset to zero
            sp[c] = s;
        }
        float* op = out + ((size_t)t * B + bg) * OUT + o0;
        *(float4*)(op)     = *(float4*)&sp[0];
        *(float4*)(op + 4) = *(float4*)&sp[4];
    }
}

extern "C" void kernel_launch(void* const* d_in, const int* in_sizes, int n_in,
                              void* d_out, int out_size, void* d_ws, size_t ws_size,
                              hipStream_t stream)
{
    const float* x    = (const float*)d_in[0];
    const float* w    = (const float*)d_in[1];
    const float* bias = (const float*)d_in[2];
    float* out = (float*)d_out;

    const int OUT = in_sizes[2];            // 4096
    const int IN  = in_sizes[1] / OUT;      // 4096
    const int BT  = in_sizes[0] / IN;       // 2048
    const int B   = BT / TSTEPS;            // 256

    dim3 grid(OUT / TILE_N, BT / TILE_M);   // (16, 32)
    spike_linear_f32seq<<<grid, 256, 0, stream>>>(x, w, bias, out, B, IN, OUT);
}

// Round 5
// 5317.207 us; speedup vs baseline: 1.0099x; 1.0099x over previous
//
#include <hip/hip_runtime.h>

// SpikeLinear: out = LIF_scan( x @ W^T + bias ) over T=8 timesteps.
//
// Numerics (DO NOT CHANGE): must reproduce numpy/OpenBLAS sgemm bit-for-bit
// because the spike threshold (memb > 1.0) is discontinuous. OpenBLAS
// accumulates each C element as a strict sequential fp32 FMA chain over
// ascending k, blocked by kc=384: per-panel register accumulation from zero,
// then C += panel (fp32 add) at k = 384, 768, ..., 3840, then bias add, LIF
// scan -- all fp32. Verified absmax == 0.0 in round 3.
//
// Perf structure (round 5): 8x8 register tile, ONE accumulator set (64 regs);
// completed kc-panels are folded into d_out (global RMW, C-sized scratch,
// L3-resident, each element touched only by its owner thread; first fold
// stores, so poison never read). Double-buffered LDS, 1 barrier per BK step,
// global prefetch one step ahead. Round-4 lesson: a second register-resident
// accumulator set spills catastrophically (26 GB scratch traffic).

constexpr int TSTEPS = 8;
constexpr int BK     = 16;
constexpr int TILE_M = 64;     // 8 batches * 8 timesteps
constexpr int TILE_N = 256;    // output columns per block
constexpr int FOLD_S = 24;     // BK steps per kc panel: 24*16 = 384 = OpenBLAS kc

__global__ __launch_bounds__(256, 2)
void spike_linear_f32seq(const float* __restrict__ x,
                         const float* __restrict__ w,
                         const float* __restrict__ bias,
                         float* __restrict__ out,
                         int B, int IN, int OUT)
{
    // k-major LDS tiles, double-buffered. +8 pad: rows stay 16B-aligned and
    // row stride is 8 banks -> staging writes are 2-way (free).
    __shared__ float xs[2][BK][TILE_M + 8];
    __shared__ float ws[2][BK][TILE_N + 8];

    const int tid = threadIdx.x;
    const int tx  = tid & 31;    // owns cols tx*4..+3 and 128+tx*4..+3
    const int ty  = tid >> 5;    // batch row within tile (owns all 8 t)

    const int m0 = blockIdx.y * TILE_M;
    const int n0 = blockIdx.x * TILE_N;

    float acc[TSTEPS][8];        // current kc-panel accumulator (only one set!)
    #pragma unroll
    for (int t = 0; t < TSTEPS; ++t)
        #pragma unroll
        for (int c = 0; c < 8; ++c) acc[t][c] = 0.f;

    // staging: thread -> (row sr, k-offset sk); one float4 of x, four of w
    const int sr = tid >> 2;         // 0..63
    const int sk = (tid & 3) * 4;    // 0,4,8,12

    const float* xrow  = x + (size_t)(m0 + sr) * IN + sk;
    const float* wrow0 = w + (size_t)(n0 +       sr) * IN + sk;
    const float* wrow1 = w + (size_t)(n0 +  64 + sr) * IN + sk;
    const float* wrow2 = w + (size_t)(n0 + 128 + sr) * IN + sk;
    const float* wrow3 = w + (size_t)(n0 + 192 + sr) * IN + sk;

    // this thread's C block in out-layout: row (t*B + bg), cols o0 / o0+128
    const int bg = blockIdx.y * 8 + ty;
    const int o0 = n0 + tx * 4;
    float* crow = out + (size_t)bg * OUT + o0;
    const size_t crstride = (size_t)B * OUT;

    // prologue: stage k-step 0 into buffer 0
    {
        const float4 xv  = *(const float4*)(xrow);
        const float4 wv0 = *(const float4*)(wrow0);
        const float4 wv1 = *(const float4*)(wrow1);
        const float4 wv2 = *(const float4*)(wrow2);
        const float4 wv3 = *(const float4*)(wrow3);
        xs[0][sk+0][sr] = xv.x;  xs[0][sk+1][sr] = xv.y;
        xs[0][sk+2][sr] = xv.z;  xs[0][sk+3][sr] = xv.w;
        ws[0][sk+0][sr]     = wv0.x; ws[0][sk+1][sr]     = wv0.y;
        ws[0][sk+2][sr]     = wv0.z; ws[0][sk+3][sr]     = wv0.w;
        ws[0][sk+0][sr+64]  = wv1.x; ws[0][sk+1][sr+64]  = wv1.y;
        ws[0][sk+2][sr+64]  = wv1.z; ws[0][sk+3][sr+64]  = wv1.w;
        ws[0][sk+0][sr+128] = wv2.x; ws[0][sk+1][sr+128] = wv2.y;
        ws[0][sk+2][sr+128] = wv2.z; ws[0][sk+3][sr+128] = wv2.w;
        ws[0][sk+0][sr+192] = wv3.x; ws[0][sk+1][sr+192] = wv3.y;
        ws[0][sk+2][sr+192] = wv3.z; ws[0][sk+3][sr+192] = wv3.w;
    }
    __syncthreads();

    const int NS = IN / BK;          // 256 steps
    int next_fold = FOLD_S;          // s = 24, 48, ..., 240

    for (int s = 0; s < NS; ++s) {
        const int buf = s & 1;
        const bool hn = (s + 1) < NS;

        // prefetch next k-step from global (latency hides under the FMAs)
        float4 xv, wv0, wv1, wv2, wv3;
        if (hn) {
            const int ko = (s + 1) * BK;
            xv  = *(const float4*)(xrow  + ko);
            wv0 = *(const float4*)(wrow0 + ko);
            wv1 = *(const float4*)(wrow1 + ko);
            wv2 = *(const float4*)(wrow2 + ko);
            wv3 = *(const float4*)(wrow3 + ko);
        }

        // kc-panel boundary: fold finished panel into C (out used as scratch).
        // First fold STORES (overwrites poison); later folds RMW. Exactly the
        // BLAS order: C += panel, panels ascending.
        if (s == next_fold) {
            next_fold += FOLD_S;
            if (s == FOLD_S) {
                #pragma unroll
                for (int t = 0; t < TSTEPS; ++t) {
                    float* cp = crow + (size_t)t * crstride;
                    *(float4*)cp         = *(float4*)&acc[t][0];
                    *(float4*)(cp + 128) = *(float4*)&acc[t][4];
                    #pragma unroll
                    for (int c = 0; c < 8; ++c) acc[t][c] = 0.f;
                }
            } else {
                #pragma unroll
                for (int t = 0; t < TSTEPS; ++t) {
                    float* cp = crow + (size_t)t * crstride;
                    float4 c0 = *(const float4*)cp;
                    float4 c1 = *(const float4*)(cp + 128);
                    c0.x += acc[t][0]; c0.y += acc[t][1];
                    c0.z += acc[t][2]; c0.w += acc[t][3];
                    c1.x += acc[t][4]; c1.y += acc[t][5];
                    c1.z += acc[t][6]; c1.w += acc[t][7];
                    *(float4*)cp         = c0;
                    *(float4*)(cp + 128) = c1;
                    #pragma unroll
                    for (int c = 0; c < 8; ++c) acc[t][c] = 0.f;
                }
            }
        }

        #pragma unroll
        for (int k = 0; k < BK; ++k) {
            float xr[8], wr[8];
            *(float4*)&xr[0] = *(const float4*)&xs[buf][k][ty*8];
            *(float4*)&xr[4] = *(const float4*)&xs[buf][k][ty*8 + 4];
            *(float4*)&wr[0] = *(const float4*)&ws[buf][k][tx*4];
            *(float4*)&wr[4] = *(const float4*)&ws[buf][k][128 + tx*4];
            #pragma unroll
            for (int t = 0; t < TSTEPS; ++t)
                #pragma unroll
                for (int c = 0; c < 8; ++c)
                    acc[t][c] = fmaf(xr[t], wr[c], acc[t][c]);
        }

        if (hn) {
            const int nb = buf ^ 1;
            xs[nb][sk+0][sr] = xv.x;  xs[nb][sk+1][sr] = xv.y;
            xs[nb][sk+2][sr] = xv.z;  xs[nb][sk+3][sr] = xv.w;
            ws[nb][sk+0][sr]     = wv0.x; ws[nb][sk+1][sr]     = wv0.y;
            ws[nb][sk+2][sr]     = wv0.z; ws[nb][sk+3][sr]     = wv0.w;
            ws[nb][sk+0][sr+64]  = wv1.x; ws[nb][sk+1][sr+64]  = wv1.y;
            ws[nb][sk+2][sr+64]  = wv1.z; ws[nb][sk+3][sr+64]  = wv1.w;
            ws[nb][sk+0][sr+128] = wv2.x; ws[nb][sk+1][sr+128] = wv2.y;
            ws[nb][sk+2][sr+128] = wv2.z; ws[nb][sk+3][sr+128] = wv2.w;
            ws[nb][sk+0][sr+192] = wv3.x; ws[nb][sk+1][sr+192] = wv3.y;
            ws[nb][sk+2][sr+192] = wv3.z; ws[nb][sk+3][sr+192] = wv3.w;
        }
        __syncthreads();
    }

    // epilogue: final panel fold (C_mem holds panels 0..9, acc holds panel 10),
    // then fp32 bias add (numpy order), fp32 LIF scan, spikes overwrite C.
    const float4 bvlo = *(const float4*)(bias + o0);
    const float4 bvhi = *(const float4*)(bias + o0 + 128);
    const float bb[8] = {bvlo.x, bvlo.y, bvlo.z, bvlo.w,
                         bvhi.x, bvhi.y, bvhi.z, bvhi.w};
    float memb[8] = {0.f, 0.f, 0.f, 0.f, 0.f, 0.f, 0.f, 0.f};
    #pragma unroll
    for (int t = 0; t < TSTEPS; ++t) {
        float* cp = crow + (size_t)t * crstride;
        float4 c0 = *(const float4*)cp;
        float4 c1 = *(const float4*)(cp + 128);
        float ctot[8] = {c0.x + acc[t][0], c0.y + acc[t][1],
                         c0.z + acc[t][2], c0.w + acc[t][3],
                         c1.x + acc[t][4], c1.y + acc[t][5],
                         c1.z + acc[t][6], c1.w + acc[t][7]};
        float sp[8];
        #pragma unroll
        for (int c = 0; c < 8; ++c) {
            float pre = ctot[c] + bb[c];
            memb[c] += pre;                          // VTHR = 1.0 (exact)
            float s = (memb[c] > 1.0f) ? 1.0f : 0.0f;
            memb[c] *= (1.0f - s);                   // reset to zero
            sp[c] = s;
        }
        *(float4*)cp         = *(float4*)&sp[0];
        *(float4*)(cp + 128) = *(float4*)&sp[4];
    }
}

extern "C" void kernel_launch(void* const* d_in, const int* in_sizes, int n_in,
                              void* d_out, int out_size, void* d_ws, size_t ws_size,
                              hipStream_t stream)
{
    const float* x    = (const float*)d_in[0];
    const float* w    = (const float*)d_in[1];
    const float* bias = (const float*)d_in[2];
    float* out = (float*)d_out;

    const int OUT = in_sizes[2];            // 4096
    const int IN  = in_sizes[1] / OUT;      // 4096
    const int BT  = in_sizes[0] / IN;       // 2048
    const int B   = BT / TSTEPS;            // 256

    dim3 grid(OUT / TILE_N, BT / TILE_M);   // (16, 32) = 512 blocks = 2/CU
    spike_linear_f32seq<<<grid, 256, 0, stream>>>(x, w, bias, out, B, IN, OUT);
}